// Round 12
// baseline (35.872 us; speedup 1.0000x reference)
//
#include <hip/hip_runtime.h>
#include <math.h>

#define TT 512
#define KP 4

typedef unsigned long long u64;

// Block-wide LDS barrier: waits DS ops only; global stores stay in flight.
#define SYNCL() asm volatile("s_waitcnt lgkmcnt(0)\n\ts_barrier" ::: "memory")
// In-wave DS fence.
#define SYNCW() do { asm volatile("s_waitcnt lgkmcnt(0)" ::: "memory"); \
                     __builtin_amdgcn_sched_barrier(0); } while (0)

// ---- transpose: x[32][512][64] -> xt[2048][512], xt[b*64+n][t] = x[b][t][n] ----
__global__ __launch_bounds__(256) void transpose_kernel(const float* __restrict__ x,
                                                        float* __restrict__ xt) {
    __shared__ float tile[64][65];
    const int b  = blockIdx.x >> 3;
    const int t0 = (blockIdx.x & 7) << 6;
    const int j  = threadIdx.x;
    #pragma unroll
    for (int it = 0; it < 4; ++it) {
        const int flat = it * 256 + j;           // 0..1023
        const int trow = flat >> 4, f4c = flat & 15;
        float4 v = *(const float4*)(x + (size_t)(b * 512 + t0 + trow) * 64 + f4c * 4);
        tile[trow][f4c * 4 + 0] = v.x;
        tile[trow][f4c * 4 + 1] = v.y;
        tile[trow][f4c * 4 + 2] = v.z;
        tile[trow][f4c * 4 + 3] = v.w;
    }
    __syncthreads();
    #pragma unroll
    for (int it = 0; it < 4; ++it) {
        const int flat = it * 256 + j;
        const int nrow = flat >> 4, f4c = flat & 15;
        float4 v;
        v.x = tile[f4c * 4 + 0][nrow];
        v.y = tile[f4c * 4 + 1][nrow];
        v.z = tile[f4c * 4 + 2][nrow];
        v.w = tile[f4c * 4 + 3][nrow];
        *(float4*)(xt + (size_t)(b * 64 + nrow) * 512 + t0 + f4c * 4) = v;
    }
}

// one block per sequence row. 256 threads = 4 waves. (R10 structure verbatim;
// only the input path differs: coalesced from xt when transposed=1.)
__global__ __launch_bounds__(256) void periodicity_kernel(const float* __restrict__ x,
                                                          const float* __restrict__ xt,
                                                          float* __restrict__ out,
                                                          int transposed) {
    const int bn   = transposed ? (int)blockIdx.x
                                : ((blockIdx.x & 7) * 256 + (blockIdx.x >> 3));
    const int tid  = threadIdx.x;    // 0..255
    const int lane = tid & 63;
    const int wid  = tid >> 6;
    const int b = bn >> 6;
    const int n = bn & 63;

    __shared__ float2 tw[TT];                       // tw[m] = e^{-2*pi*i*m/512}
    __shared__ __align__(16) float row[TT];         // natural order
    __shared__ __align__(16) float2 buf[TT];        // FFT working buffer
    __shared__ __align__(16) u64 keys[256];         // (mag_bits<<32)|(256-f)
    __shared__ double candV8[8];

    // ---- twiddles (one sincosf/thread) ----
    float sv, cv;
    sincosf((float)(2.0 * M_PI / 512.0) * (float)tid, &sv, &cv);
    tw[tid]       = make_float2(cv, -sv);
    tw[tid + 256] = make_float2(-cv, sv);

    // ---- load row + folded radix-2 first DIF stage ----
    {
        float v0, v1;
        if (transposed) {
            const float* xr = xt + (size_t)bn * TT;
            v0 = xr[tid];
            v1 = xr[tid + 256];
        } else {
            const float* xb = x + (size_t)b * (TT * 64) + n;
            v0 = xb[(size_t)tid * 64];
            v1 = xb[(size_t)(tid + 256) * 64];
        }
        row[tid] = v0;  row[tid + 256] = v1;
        float sum = v0 + v1, dif = v0 - v1;
        buf[tid]       = make_float2(sum, 0.f);
        buf[tid + 256] = make_float2(dif * cv, -dif * sv);
    }
    SYNCL();   // barrier 1: buf/row/tw ready

    // ---- wave-local FFT: wave h owns 256-half h; in-wave fences only ----
    if (wid < 2) {
        const int h = wid;
        float2* bb = &buf[h << 8];

        #pragma unroll
        for (int stg = 0; stg < 3; ++stg) {
            const int Q  = 64 >> (2 * stg);          // 64,16,4
            const int g  = lane >> (6 - 2 * stg);
            const int i  = lane & (Q - 1);
            const int base = g * (Q << 2) + i;
            float2 x0 = bb[base],         x1 = bb[base + Q];
            float2 x2 = bb[base + 2 * Q], x3 = bb[base + 3 * Q];
            float2 A  = make_float2(x0.x + x2.x, x0.y + x2.y);
            float2 Bm = make_float2(x0.x - x2.x, x0.y - x2.y);
            float2 Cc = make_float2(x1.x + x3.x, x1.y + x3.y);
            float2 D  = make_float2(x1.x - x3.x, x1.y - x3.y);
            float2 y0 = make_float2(A.x + Cc.x, A.y + Cc.y);
            float2 y2 = make_float2(A.x - Cc.x, A.y - Cc.y);
            float2 y1 = make_float2(Bm.x + D.y, Bm.y - D.x);   // Bm - i*D
            float2 y3 = make_float2(Bm.x - D.y, Bm.y + D.x);   // Bm + i*D
            const int m = i << (1 + 2 * stg);
            float2 t1 = tw[m], t2 = tw[2 * m], t3 = tw[3 * m];
            bb[base]         = y0;
            bb[base + Q]     = make_float2(y1.x * t1.x - y1.y * t1.y, y1.x * t1.y + y1.y * t1.x);
            bb[base + 2 * Q] = make_float2(y2.x * t2.x - y2.y * t2.y, y2.x * t2.y + y2.y * t2.x);
            bb[base + 3 * Q] = make_float2(y3.x * t3.x - y3.y * t3.y, y3.x * t3.y + y3.y * t3.x);
            SYNCW();
        }

        // stage 3 (Q=1, twiddles=1) fused with mag^2 + vectorized key write
        {
            const int g = lane;
            const int base = g << 2;
            float2 x0 = bb[base],     x1 = bb[base + 1];
            float2 x2 = bb[base + 2], x3 = bb[base + 3];
            float2 A  = make_float2(x0.x + x2.x, x0.y + x2.y);
            float2 Bm = make_float2(x0.x - x2.x, x0.y - x2.y);
            float2 Cc = make_float2(x1.x + x3.x, x1.y + x3.y);
            float2 D  = make_float2(x1.x - x3.x, x1.y - x3.y);
            float2 y0 = make_float2(A.x + Cc.x, A.y + Cc.y);
            float2 y2 = make_float2(A.x - Cc.x, A.y - Cc.y);
            float2 y1 = make_float2(Bm.x + D.y, Bm.y - D.x);
            float2 y3 = make_float2(Bm.x - D.y, Bm.y + D.x);
            const int revg = ((g & 3) << 4) | (((g >> 2) & 3) << 2) | ((g >> 4) & 3);
            const int f0 = 2 * revg + h;
            float m0 = y0.x * y0.x + y0.y * y0.y;
            float m1 = y1.x * y1.x + y1.y * y1.y;
            float m2 = y2.x * y2.x + y2.y * y2.y;
            u64 kA, kB;
            if (f0 == 0) {   // (h=0,g=0): keep f=128, f=256
                kA = ((u64)__float_as_uint(m1) << 32) | (u64)(256 - 128);
                kB = ((u64)__float_as_uint(m2) << 32) | (u64)(256 - 256);
            } else {         // keep f0, f0+128
                kA = ((u64)__float_as_uint(m0) << 32) | (u64)(256 - f0);
                kB = ((u64)__float_as_uint(m1) << 32) | (u64)(256 - (f0 + 128));
            }
            ((ulonglong2*)keys)[(h << 6) + g] = make_ulonglong2(kA, kB);
        }
    }
    SYNCL();   // barrier 2: keys ready

    // ---- redundant per-wave top-8 (every wave; results in registers) ----
    int   fbin[8];
    float cmag[8];
    {
        const ulonglong2* kv = (const ulonglong2*)keys;
        ulonglong2 p0v = kv[lane * 2];
        ulonglong2 p1v = kv[lane * 2 + 1];
        u64 k0 = p0v.x, k1 = p0v.y, k2 = p1v.x, k3 = p1v.y;
        #define CSWAP(a, b) { if (a < b) { u64 _t = a; a = b; b = _t; } }
        CSWAP(k0, k1) CSWAP(k2, k3) CSWAP(k0, k2) CSWAP(k1, k3) CSWAP(k1, k2)
        #undef CSWAP
        #pragma unroll
        for (int r = 0; r < 8; ++r) {
            u64 w = k0;
            #pragma unroll
            for (int off = 32; off >= 1; off >>= 1) {
                u64 o = __shfl_xor(w, off);
                if (o > w) w = o;
            }
            if (k0 == w) { k0 = k1; k1 = k2; k2 = k3; k3 = 0; }
            fbin[r] = 256 - (int)(w & 0xff);
            cmag[r] = __uint_as_float((unsigned)(w >> 32));
        }
    }

    // ---- gap check: fp32 ranking provably exact? (uniform across block) ----
    int per[KP], cycv[KP], stv[KP];
    {
        const bool needRefine =
            ((cmag[0] - cmag[1]) <= 1e-4f * cmag[0]) || ((cmag[1] - cmag[2]) <= 1e-4f * cmag[1]) ||
            ((cmag[2] - cmag[3]) <= 1e-4f * cmag[2]) || ((cmag[3] - cmag[4]) <= 1e-4f * cmag[3]);
        int bins[KP];
        if (!needRefine) {
            #pragma unroll
            for (int k = 0; k < KP; ++k) bins[k] = fbin[k];
        } else {
            // ---- f64 refine of the 8 candidates (rare; exact ranking) ----
            {
                const int cid = tid >> 5;        // candidate 0..7
                const int sub = tid & 31;
                int fc;
                switch (cid) {                   // static indices (rule #20)
                    case 0: fc = fbin[0]; break;
                    case 1: fc = fbin[1]; break;
                    case 2: fc = fbin[2]; break;
                    case 3: fc = fbin[3]; break;
                    case 4: fc = fbin[4]; break;
                    case 5: fc = fbin[5]; break;
                    case 6: fc = fbin[6]; break;
                    default: fc = fbin[7]; break;
                }
                const int t0 = sub * 16;
                const double W = 6.2831853071795864769 / 512.0;
                double zr, zi, wr, wi;
                sincos(W * (double)((fc * t0) & 511), &zi, &zr);
                sincos(W * (double)fc, &wi, &wr);
                double ar = 0.0, ai = 0.0;
                const float4* r4 = (const float4*)row;
                #pragma unroll
                for (int v4i = 0; v4i < 4; ++v4i) {
                    float4 xv = r4[sub * 4 + v4i];
                    #define STEP(comp)                                   \
                        { double xd = (double)xv.comp;                   \
                          ar = fma(xd, zr, ar); ai = fma(xd, zi, ai);    \
                          double tq = zr * wr - zi * wi;                 \
                          zi = fma(zr, wi, zi * wr); zr = tq; }
                    STEP(x) STEP(y) STEP(z) STEP(w)
                    #undef STEP
                }
                #pragma unroll
                for (int off = 16; off >= 1; off >>= 1) {
                    ar += __shfl_xor(ar, off);
                    ai += __shfl_xor(ai, off);
                }
                if (sub == 0) candV8[cid] = ar * ar + ai * ai;
            }
            SYNCL();
            unsigned chosen = 0;
            #pragma unroll
            for (int k = 0; k < KP; ++k) {
                double bv = -1.0; int bbin = 0x7fffffff; int bj = 0;
                #pragma unroll
                for (int j = 0; j < 8; ++j) {
                    if (chosen & (1u << j)) continue;
                    double vj = candV8[j];
                    int    bjn = fbin[j];
                    if (vj > bv || (vj == bv && bjn < bbin)) { bv = vj; bbin = bjn; bj = j; }
                }
                chosen |= (1u << bj);
                bins[k] = bbin;
            }
        }
        #pragma unroll
        for (int k = 0; k < KP; ++k) {
            int p = TT / bins[k];
            p = p < 8 ? 8 : (p > 64 ? 64 : p);
            per[k]  = p;
            cycv[k] = TT / p;
            stv[k]  = TT - cycv[k] * p;
        }
    }

    const size_t VOFF = (size_t)2048 * KP * 64 * 64;   // 33,554,432
    if (tid == 0) {
        #pragma unroll
        for (int k = 0; k < KP; ++k) {
            out[VOFF + (size_t)bn * KP + k]        = (float)per[k];
            out[VOFF + 8192 + (size_t)bn * KP + k] = (float)cycv[k];
        }
    }

    // ---- gather + vectorized dense store: values[bn, k, c, p] ----
    float* outv = out + (size_t)bn * (KP * 64 * 64);
    const int c_local = tid >> 4;
    const int p0 = (tid & 15) << 2;
    #pragma unroll
    for (int it = 0; it < 16; ++it) {
        const int k = it >> 2;
        const int c = ((it & 3) << 4) + c_local;
        float4 v = make_float4(0.f, 0.f, 0.f, 0.f);
        const int P = per[k], C = cycv[k], S0 = stv[k];
        if (c < C) {
            const int base = S0 + c * P;
            if (p0 + 3 < P) {
                v.x = row[base + p0];
                v.y = row[base + p0 + 1];
                v.z = row[base + p0 + 2];
                v.w = row[base + p0 + 3];
            } else {
                if (p0     < P) v.x = row[base + p0];
                if (p0 + 1 < P) v.y = row[base + p0 + 1];
                if (p0 + 2 < P) v.z = row[base + p0 + 2];
                if (p0 + 3 < P) v.w = row[base + p0 + 3];
            }
        }
        *(float4*)(outv + (size_t)it * 1024 + (size_t)tid * 4) = v;
    }
}

extern "C" void kernel_launch(void* const* d_in, const int* in_sizes, int n_in,
                              void* d_out, int out_size, void* d_ws, size_t ws_size,
                              hipStream_t stream) {
    const float* x = (const float*)d_in[0];
    float* out = (float*)d_out;
    const size_t xt_bytes = (size_t)2048 * 512 * sizeof(float);   // 4 MB
    if (ws_size >= xt_bytes) {
        float* xt = (float*)d_ws;
        hipLaunchKernelGGL(transpose_kernel, dim3(256), dim3(256), 0, stream, x, xt);
        hipLaunchKernelGGL(periodicity_kernel, dim3(2048), dim3(256), 0, stream, x, xt, out, 1);
    } else {
        hipLaunchKernelGGL(periodicity_kernel, dim3(2048), dim3(256), 0, stream, x, (const float*)nullptr, out, 0);
    }
}

// Round 13
// 33.420 us; speedup vs baseline: 1.0734x; 1.0734x over previous
//
#include <hip/hip_runtime.h>
#include <math.h>

#define TT 512
#define KP 4

typedef unsigned long long u64;

// Block-wide LDS barrier: waits DS ops only; global stores stay in flight.
#define SYNCL() asm volatile("s_waitcnt lgkmcnt(0)\n\ts_barrier" ::: "memory")
// In-wave DS fence.
#define SYNCW() do { asm volatile("s_waitcnt lgkmcnt(0)" ::: "memory"); \
                     __builtin_amdgcn_sched_barrier(0); } while (0)

// 1024 blocks x 256 threads (4 waves). Block owns rows bn = blk*2 + {0,1},
// processed serially; row-0 stores drain under row-1 compute (lgkm-only
// barriers never wait vmcnt).
__global__ __launch_bounds__(256) void periodicity_kernel(const float* __restrict__ x,
                                                          float* __restrict__ out) {
    const int blk  = blockIdx.x;     // 0..1023
    const int tid  = threadIdx.x;    // 0..255
    const int lane = tid & 63;
    const int wid  = tid >> 6;

    __shared__ float2 tw[TT];                       // tw[m] = e^{-2*pi*i*m/512}
    __shared__ __align__(16) float row[TT];         // natural order (current row)
    __shared__ __align__(16) float2 buf[TT];        // FFT working buffer
    __shared__ __align__(16) u64 keys[256];         // (mag_bits<<32)|(256-f)
    __shared__ double candV8[8];

    // ---- twiddles (one sincosf/thread) ----
    float sv, cv;
    sincosf((float)(2.0 * M_PI / 512.0) * (float)tid, &sv, &cv);
    tw[tid]       = make_float2(cv, -sv);
    tw[tid + 256] = make_float2(-cv, sv);

    // ---- prefetch BOTH rows' input into registers (strided column loads) ----
    const int bn0 = blk * 2;
    const float* xb0 = x + (size_t)(bn0 >> 6) * (TT * 64) + (bn0 & 63);
    const float* xb1 = xb0 + 1;                     // adjacent channel
    float a0 = xb0[(size_t)tid * 64];
    float a1 = xb0[(size_t)(tid + 256) * 64];
    float b0 = xb1[(size_t)tid * 64];
    float b1 = xb1[(size_t)(tid + 256) * 64];

    const size_t VOFF = (size_t)2048 * KP * 64 * 64;   // 33,554,432

    #pragma unroll
    for (int r = 0; r < 2; ++r) {
        const int bn = bn0 + r;
        const float v0 = r ? b0 : a0;
        const float v1 = r ? b1 : a1;

        SYNCL();   // previous row's LDS readers done (r=0: tw ready)

        // ---- stage row + folded radix-2 first DIF stage ----
        {
            row[tid] = v0;  row[tid + 256] = v1;
            float sum = v0 + v1, dif = v0 - v1;
            float2 t = tw[tid];
            buf[tid]       = make_float2(sum, 0.f);
            buf[tid + 256] = make_float2(dif * t.x, dif * t.y);
        }
        SYNCL();   // buf/row ready

        // ---- wave-local FFT: wave h owns 256-half h; in-wave fences only ----
        if (wid < 2) {
            const int h = wid;
            float2* bb = &buf[h << 8];

            #pragma unroll
            for (int stg = 0; stg < 3; ++stg) {
                const int Q  = 64 >> (2 * stg);          // 64,16,4
                const int g  = lane >> (6 - 2 * stg);
                const int i  = lane & (Q - 1);
                const int base = g * (Q << 2) + i;
                float2 x0 = bb[base],         x1 = bb[base + Q];
                float2 x2 = bb[base + 2 * Q], x3 = bb[base + 3 * Q];
                float2 A  = make_float2(x0.x + x2.x, x0.y + x2.y);
                float2 Bm = make_float2(x0.x - x2.x, x0.y - x2.y);
                float2 Cc = make_float2(x1.x + x3.x, x1.y + x3.y);
                float2 D  = make_float2(x1.x - x3.x, x1.y - x3.y);
                float2 y0 = make_float2(A.x + Cc.x, A.y + Cc.y);
                float2 y2 = make_float2(A.x - Cc.x, A.y - Cc.y);
                float2 y1 = make_float2(Bm.x + D.y, Bm.y - D.x);   // Bm - i*D
                float2 y3 = make_float2(Bm.x - D.y, Bm.y + D.x);   // Bm + i*D
                const int m = i << (1 + 2 * stg);
                float2 t1 = tw[m], t2 = tw[2 * m], t3 = tw[3 * m];
                bb[base]         = y0;
                bb[base + Q]     = make_float2(y1.x * t1.x - y1.y * t1.y, y1.x * t1.y + y1.y * t1.x);
                bb[base + 2 * Q] = make_float2(y2.x * t2.x - y2.y * t2.y, y2.x * t2.y + y2.y * t2.x);
                bb[base + 3 * Q] = make_float2(y3.x * t3.x - y3.y * t3.y, y3.x * t3.y + y3.y * t3.x);
                SYNCW();
            }

            // stage 3 (Q=1, twiddles=1) fused with mag^2 + vectorized key write
            {
                const int g = lane;
                const int base = g << 2;
                float2 x0 = bb[base],     x1 = bb[base + 1];
                float2 x2 = bb[base + 2], x3 = bb[base + 3];
                float2 A  = make_float2(x0.x + x2.x, x0.y + x2.y);
                float2 Bm = make_float2(x0.x - x2.x, x0.y - x2.y);
                float2 Cc = make_float2(x1.x + x3.x, x1.y + x3.y);
                float2 D  = make_float2(x1.x - x3.x, x1.y - x3.y);
                float2 y0 = make_float2(A.x + Cc.x, A.y + Cc.y);
                float2 y2 = make_float2(A.x - Cc.x, A.y - Cc.y);
                float2 y1 = make_float2(Bm.x + D.y, Bm.y - D.x);
                float2 y3 = make_float2(Bm.x - D.y, Bm.y + D.x);
                const int revg = ((g & 3) << 4) | (((g >> 2) & 3) << 2) | ((g >> 4) & 3);
                const int f0 = 2 * revg + h;
                float m0 = y0.x * y0.x + y0.y * y0.y;
                float m1 = y1.x * y1.x + y1.y * y1.y;
                float m2 = y2.x * y2.x + y2.y * y2.y;
                u64 kA, kB;
                if (f0 == 0) {   // (h=0,g=0): keep f=128, f=256
                    kA = ((u64)__float_as_uint(m1) << 32) | (u64)(256 - 128);
                    kB = ((u64)__float_as_uint(m2) << 32) | (u64)(256 - 256);
                } else {         // keep f0, f0+128
                    kA = ((u64)__float_as_uint(m0) << 32) | (u64)(256 - f0);
                    kB = ((u64)__float_as_uint(m1) << 32) | (u64)(256 - (f0 + 128));
                }
                ((ulonglong2*)keys)[(h << 6) + g] = make_ulonglong2(kA, kB);
            }
        }
        SYNCL();   // keys ready

        // ---- redundant per-wave top-8 (every wave; results in registers) ----
        int   fbin[8];
        float cmag[8];
        {
            const ulonglong2* kv = (const ulonglong2*)keys;
            ulonglong2 p0v = kv[lane * 2];
            ulonglong2 p1v = kv[lane * 2 + 1];
            u64 k0 = p0v.x, k1 = p0v.y, k2 = p1v.x, k3 = p1v.y;
            #define CSWAP(a, b) { if (a < b) { u64 _t = a; a = b; b = _t; } }
            CSWAP(k0, k1) CSWAP(k2, k3) CSWAP(k0, k2) CSWAP(k1, k3) CSWAP(k1, k2)
            #undef CSWAP
            #pragma unroll
            for (int rr = 0; rr < 8; ++rr) {
                u64 w = k0;
                #pragma unroll
                for (int off = 32; off >= 1; off >>= 1) {
                    u64 o = __shfl_xor(w, off);
                    if (o > w) w = o;
                }
                if (k0 == w) { k0 = k1; k1 = k2; k2 = k3; k3 = 0; }
                fbin[rr] = 256 - (int)(w & 0xff);
                cmag[rr] = __uint_as_float((unsigned)(w >> 32));
            }
        }

        // ---- gap check + (rare) f64 refine ----
        int per[KP], cycv[KP], stv[KP];
        {
            const bool needRefine =
                ((cmag[0] - cmag[1]) <= 1e-4f * cmag[0]) || ((cmag[1] - cmag[2]) <= 1e-4f * cmag[1]) ||
                ((cmag[2] - cmag[3]) <= 1e-4f * cmag[2]) || ((cmag[3] - cmag[4]) <= 1e-4f * cmag[3]);
            int bins[KP];
            if (!needRefine) {
                #pragma unroll
                for (int k = 0; k < KP; ++k) bins[k] = fbin[k];
            } else {
                {
                    const int cid = tid >> 5;        // candidate 0..7
                    const int sub = tid & 31;
                    int fc;
                    switch (cid) {                   // static indices (rule #20)
                        case 0: fc = fbin[0]; break;
                        case 1: fc = fbin[1]; break;
                        case 2: fc = fbin[2]; break;
                        case 3: fc = fbin[3]; break;
                        case 4: fc = fbin[4]; break;
                        case 5: fc = fbin[5]; break;
                        case 6: fc = fbin[6]; break;
                        default: fc = fbin[7]; break;
                    }
                    const int t0 = sub * 16;
                    const double W = 6.2831853071795864769 / 512.0;
                    double zr, zi, wr, wi;
                    sincos(W * (double)((fc * t0) & 511), &zi, &zr);
                    sincos(W * (double)fc, &wi, &wr);
                    double ar = 0.0, ai = 0.0;
                    const float4* r4 = (const float4*)row;
                    #pragma unroll
                    for (int v4i = 0; v4i < 4; ++v4i) {
                        float4 xv = r4[sub * 4 + v4i];
                        #define STEP(comp)                                   \
                            { double xd = (double)xv.comp;                   \
                              ar = fma(xd, zr, ar); ai = fma(xd, zi, ai);    \
                              double tq = zr * wr - zi * wi;                 \
                              zi = fma(zr, wi, zi * wr); zr = tq; }
                        STEP(x) STEP(y) STEP(z) STEP(w)
                        #undef STEP
                    }
                    #pragma unroll
                    for (int off = 16; off >= 1; off >>= 1) {
                        ar += __shfl_xor(ar, off);
                        ai += __shfl_xor(ai, off);
                    }
                    if (sub == 0) candV8[cid] = ar * ar + ai * ai;
                }
                SYNCL();
                unsigned chosen = 0;
                #pragma unroll
                for (int k = 0; k < KP; ++k) {
                    double bv = -1.0; int bbin = 0x7fffffff; int bj = 0;
                    #pragma unroll
                    for (int j = 0; j < 8; ++j) {
                        if (chosen & (1u << j)) continue;
                        double vj = candV8[j];
                        int    bjn = fbin[j];
                        if (vj > bv || (vj == bv && bjn < bbin)) { bv = vj; bbin = bjn; bj = j; }
                    }
                    chosen |= (1u << bj);
                    bins[k] = bbin;
                }
            }
            #pragma unroll
            for (int k = 0; k < KP; ++k) {
                int p = TT / bins[k];
                p = p < 8 ? 8 : (p > 64 ? 64 : p);
                per[k]  = p;
                cycv[k] = TT / p;
                stv[k]  = TT - cycv[k] * p;
            }
        }

        if (tid == 0) {
            #pragma unroll
            for (int k = 0; k < KP; ++k) {
                out[VOFF + (size_t)bn * KP + k]        = (float)per[k];
                out[VOFF + 8192 + (size_t)bn * KP + k] = (float)cycv[k];
            }
        }

        // ---- gather + vectorized dense store (stores stay in flight) ----
        float* outv = out + (size_t)bn * (KP * 64 * 64);
        const int c_local = tid >> 4;
        const int p0 = (tid & 15) << 2;
        #pragma unroll
        for (int it = 0; it < 16; ++it) {
            const int k = it >> 2;
            const int c = ((it & 3) << 4) + c_local;
            float4 v = make_float4(0.f, 0.f, 0.f, 0.f);
            const int P = per[k], C = cycv[k], S0 = stv[k];
            if (c < C) {
                const int base = S0 + c * P;
                if (p0 + 3 < P) {
                    v.x = row[base + p0];
                    v.y = row[base + p0 + 1];
                    v.z = row[base + p0 + 2];
                    v.w = row[base + p0 + 3];
                } else {
                    if (p0     < P) v.x = row[base + p0];
                    if (p0 + 1 < P) v.y = row[base + p0 + 1];
                    if (p0 + 2 < P) v.z = row[base + p0 + 2];
                    if (p0 + 3 < P) v.w = row[base + p0 + 3];
                }
            }
            *(float4*)(outv + (size_t)it * 1024 + (size_t)tid * 4) = v;
        }
    }
}

extern "C" void kernel_launch(void* const* d_in, const int* in_sizes, int n_in,
                              void* d_out, int out_size, void* d_ws, size_t ws_size,
                              hipStream_t stream) {
    const float* x = (const float*)d_in[0];
    float* out = (float*)d_out;
    hipLaunchKernelGGL(periodicity_kernel, dim3(1024), dim3(256), 0, stream, x, out);
}